// Round 14
// baseline (56.940 us; speedup 1.0000x reference)
//
#include <hip/hip_runtime.h>

#define NN    16384
#define CBN   64
#define SUBV  16
#define KCODE 16
#define DOUTN 1024
#define DEP   4

typedef short bf16x8 __attribute__((ext_vector_type(8)));
typedef float f32x16 __attribute__((ext_vector_type(16)));

static __device__ __forceinline__ unsigned short f2bf(float f) {
  unsigned int u = __float_as_uint(f);
  u += 0x7FFFu + ((u >> 16) & 1u);   // RNE; inputs are normal randn, no NaN/Inf
  return (unsigned short)(u >> 16);
}

// global -> LDS direct copy, 16B/lane. LDS dest wave-uniform (HW adds lane*16).
static __device__ __forceinline__ void gld16(const void* g, void* l) {
  __builtin_amdgcn_global_load_lds(
      (const __attribute__((address_space(1))) unsigned int*)g,
      (__attribute__((address_space(3))) unsigned int*)(uintptr_t)l, 16, 0, 0);
}

// ---------------- kernel 1: table convert/swizzle + DIRECT-LINE encode ------
// blocks [0,64): build Tswz (R10 code, proven). blocks [64, 64+1024): encode
// 16 rows each. Key fact: a subvec = exactly one aligned 64-B line, and the
// tree's ELEMENT indices are depth-fixed (only thresholds are path-dependent)
// -> the 4 loads/row/c are independent scalars on one line. 16 independent
// loads/thread, no xs staging, no x barrier, 9 KiB LDS -> high occupancy,
// HBM-floor-bound (~10.2 us for the 64 MiB of touched lines).
__global__ __launch_bounds__(256) void prep_k(
    const float* __restrict__ x, const int* __restrict__ split_idxs,
    const float* __restrict__ split_vals, const float* __restrict__ Tg,
    unsigned char* __restrict__ codes, unsigned int* __restrict__ Tswz) {
  const int t = threadIdx.x;

  if (blockIdx.x < 64) {
    const int img = blockIdx.x;                   // = g8*8 + ch
    const int g = img >> 3, ch = img & 7;
    unsigned int* dst = Tswz + (size_t)img * 8192; // 8192 u32 = 32 KiB image
    const int colq = t & 31, kp = (t >> 5) & 7;
    #pragma unroll
    for (int cl = 0; cl < 8; ++cl) {
      const float* g0 = Tg + ((size_t)((ch * 8 + cl) * KCODE + 2 * kp)) * DOUTN
                        + g * 128 + colq * 4;
      float4 r0 = *(const float4*)g0;             // k=2kp   (coalesced)
      float4 r1 = *(const float4*)(g0 + DOUTN);   // k=2kp+1
      unsigned int pk[4] = {
        f2bf(r0.x) | ((unsigned int)f2bf(r1.x) << 16),
        f2bf(r0.y) | ((unsigned int)f2bf(r1.y) << 16),
        f2bf(r0.z) | ((unsigned int)f2bf(r1.z) << 16),
        f2bf(r0.w) | ((unsigned int)f2bf(r1.w) << 16)};
      unsigned key = (unsigned)(colq & 7) << 2;   // XOR on u32-idx bits[4:2]
      #pragma unroll
      for (int j = 0; j < 4; ++j)
        dst[cl * 1024 + ((((unsigned)(colq * 4 + j)) * 8 + (unsigned)kp) ^ key)]
            = pk[j];
    }
    return;
  }

  // ---- direct-line encode: 16 rows/block; thread = (c, 4 rows) ----
  __shared__ int   sidxT[DEP * CBN];               // [d][c]
  __shared__ float svalT[DEP * (KCODE / 2) * CBN]; // [d][e][c] (bank = c&31)
  if (t < DEP * CBN) {
    int d = t >> 6, c = t & 63;
    sidxT[t] = split_idxs[c * DEP + d];
  }
  #pragma unroll
  for (int i = 0; i < 8; ++i) {
    int idx = t + i * 256;
    int c = idx & 63, de = idx >> 6, d = de >> 3, e = de & 7;
    svalT[idx] = split_vals[(c * DEP + d) * (KCODE / 2) + e];
  }
  __syncthreads();

  const int c = t & 63, rg = t >> 6;               // 4 row-groups x 4 rows
  const size_t r0 = (size_t)(blockIdx.x - 64) * 16 + rg * 4;
  const float* xr = x + r0 * DOUTN + c * SUBV;
  const int si0 = sidxT[c],       si1 = sidxT[64 + c],
            si2 = sidxT[128 + c], si3 = sidxT[192 + c];
  float xv[4][4];
  #pragma unroll
  for (int i = 0; i < 4; ++i) {                    // 16 independent loads
    const float* xri = xr + (size_t)i * DOUTN;     // all 4 on ONE 64-B line
    xv[i][0] = xri[si0]; xv[i][1] = xri[si1];
    xv[i][2] = xri[si2]; xv[i][3] = xri[si3];
  }
  #pragma unroll
  for (int i = 0; i < 4; ++i) {
    int e = 0;
    #pragma unroll
    for (int d = 0; d < DEP; ++d) {
      float th = svalT[(d * 8 + e) * 64 + c];
      e = 2 * e + (xv[i][d] > th ? 1 : 0);
    }
    codes[(r0 + i) * CBN + c] = (unsigned char)e;
  }
}

// ---------------- kernel 2: one-hot MFMA gather-accumulate ----------------
// grid (16 colgroups, 32 rowgroups of 512) = 512 blocks; 512 thr = 8 waves;
// 128 KiB LDS -> 1 block/CU resident -> EXACTLY 2 sequential rounds per CU.
// Rationale (R13 decomposition): the 64 MiB output write was a fully-exposed
// ~10.6 us tail (all blocks finish together). Waves retire at s_endpgm
// without draining stores, so round-1's write burst drains UNDER round-2's
// stage+compute; only round-2's ~5.3 us tail stays exposed. Round-2 stages
// the same L2-hot image. Per-wave compute = R13 verbatim (64x64 wave,
// rt=2 x ct=2, u64-shift A-build, one-ahead prefetch, bias-in-acc,
// one barrier, ch-stagger = wid).
__global__ __launch_bounds__(512, 2) void maddness_mfma(
    const unsigned int* __restrict__ Tswz, const float* __restrict__ bias,
    const unsigned char* __restrict__ codes, float* __restrict__ out) {
  __shared__ __align__(16) unsigned int Tb[32768];   // 128 KiB: [ch8][cl8][512 u32]

  const int t = threadIdx.x;
  const int wid = t >> 6, lane = t & 63, lrow = lane & 31, h = lane >> 5;
  const int g16 = blockIdx.x, g8 = g16 >> 1, half = g16 & 1;
  const int n0 = blockIdx.y * 512;
  const char* img = (const char*)Tswz + (size_t)g8 * 8 * 32768;

  // stage: 128 segs of 1024 B over 8 waves -> wave wid stages chunk ch=wid
  #pragma unroll
  for (int i = 0; i < 16; ++i) {
    int gs = wid * 16 + i;                     // ch = wid, s16 = i
    int cl = i >> 1, pc = i & 1;
    gld16(img + wid * 32768 + cl * 4096 + half * 2048 + pc * 1024 + lane * 16,
          (char*)Tb + gs * 1024);
  }

  // bias folded into acc init (col is lane-constant)
  const float bv0 = bias[g16 * 64 + lrow];
  const float bv1 = bias[g16 * 64 + 32 + lrow];
  f32x16 acc[2][2];
  #pragma unroll
  for (int rt = 0; rt < 2; ++rt)
    #pragma unroll
    for (int e = 0; e < 16; ++e) { acc[rt][0][e] = bv0; acc[rt][1][e] = bv1; }

  const unsigned char* crow0 = codes + (size_t)(n0 + wid * 64 + lrow) * CBN;
  const unsigned char* crow1 = crow0 + 32 * CBN;
  const unsigned h2 = 2u * (unsigned)h, h2p = h2 + 1u;
  const unsigned rb0 = ((unsigned)lrow * 16 + (unsigned)h * 8)
                     ^ ((((unsigned)lrow >> 2) & 7u) << 3);
  const unsigned cl32 = (unsigned)lrow + 32u;
  const unsigned rb1 = (cl32 * 16 + (unsigned)h * 8)
                     ^ (((cl32 >> 2) & 7u) << 3);

  __syncthreads();                                  // the ONLY barrier

  // software pipeline heads: codes for i=0, B-frags for (i=0, cl=0)
  const int ch0 = wid;                              // stagger = own staged chunk
  unsigned long long qA0 = *(const unsigned long long*)(crow0 + ch0 * 8);
  unsigned long long qA1 = *(const unsigned long long*)(crow1 + ch0 * 8);
  const unsigned short* tbc = (const unsigned short*)Tb + ch0 * 8192;
  bf16x8 bP0 = *(const bf16x8*)(tbc + rb0);
  bf16x8 bP1 = *(const bf16x8*)(tbc + rb1);

  #pragma unroll
  for (int i = 0; i < 8; ++i) {
    const int chn = (wid + i + 1) & 7;
    const unsigned short* tbn = (const unsigned short*)Tb + chn * 8192;
    const unsigned long long q0 = qA0, q1 = qA1;
    if (i < 7) {                                    // prefetch next codes
      qA0 = *(const unsigned long long*)(crow0 + chn * 8);
      qA1 = *(const unsigned long long*)(crow1 + chn * 8);
    }
    #pragma unroll
    for (int cl = 0; cl < 8; ++cl) {
      const bf16x8 b0 = bP0, b1 = bP1;
      if (!(i == 7 && cl == 7)) {                   // prefetch next B-frags
        const unsigned short* tnx = (cl == 7) ? tbn : (tbc + (cl + 1) * 1024);
        bP0 = *(const bf16x8*)(tnx + rb0);
        bP1 = *(const bf16x8*)(tnx + rb1);
      }
      #pragma unroll
      for (int rt = 0; rt < 2; ++rt) {
        const unsigned q32 =
            (unsigned)((rt ? q1 : q0) >> ((cl & 4) ? 32 : 0));
        const unsigned bpos = 8u * (unsigned)(cl & 3);
        const unsigned sh  = (q32 >> bpos) & 3u;        // c & 3
        const unsigned key = (q32 >> (bpos + 2)) & 3u;  // c >> 2
        const unsigned long long tt = 0x3F80ULL << (sh << 4);
        union { unsigned long long q[2]; bf16x8 v; } A;
        A.q[0] = (key == h2)  ? tt : 0ULL;
        A.q[1] = (key == h2p) ? tt : 0ULL;
        acc[rt][0] = __builtin_amdgcn_mfma_f32_32x32x16_bf16(A.v, b0, acc[rt][0], 0, 0, 0);
        acc[rt][1] = __builtin_amdgcn_mfma_f32_32x32x16_bf16(A.v, b1, acc[rt][1], 0, 0, 0);
      }
    }
    tbc = tbn;
  }

  // single epilogue (bias already in acc):
  // D layout col=lane&31, row=(reg&3)+8*(reg>>2)+4*(lane>>5)
  #pragma unroll
  for (int ct = 0; ct < 2; ++ct) {
    const int col = g16 * 64 + ct * 32 + lrow;
    #pragma unroll
    for (int rt = 0; rt < 2; ++rt)
      #pragma unroll
      for (int r = 0; r < 16; ++r) {
        int row = n0 + wid * 64 + rt * 32 + (r & 3) + 8 * (r >> 2) + 4 * h;
        out[(size_t)row * DOUTN + col] = acc[rt][ct][r];
      }
  }
}

extern "C" void kernel_launch(void* const* d_in, const int* in_sizes, int n_in,
                              void* d_out, int out_size, void* d_ws, size_t ws_size,
                              hipStream_t stream) {
  const float* x    = (const float*)d_in[0];
  const int*   sidx = (const int*)d_in[1];
  const float* sval = (const float*)d_in[2];
  const float* Tg   = (const float*)d_in[3];
  const float* bias = (const float*)d_in[4];
  float* out = (float*)d_out;
  unsigned char* codes = (unsigned char*)d_ws;                       // 1 MiB
  unsigned int*  Tswz  = (unsigned int*)((char*)d_ws + (1 << 20));   // 2 MiB

  prep_k<<<64 + NN / 16, 256, 0, stream>>>(x, sidx, sval, Tg, codes, Tswz);
  maddness_mfma<<<dim3(16, 32), 512, 0, stream>>>(Tswz, bias, codes, out);
}

// Round 15
// 53.073 us; speedup vs baseline: 1.0729x; 1.0729x over previous
//
#include <hip/hip_runtime.h>

#define NN    16384
#define CBN   64
#define SUBV  16
#define KCODE 16
#define DOUTN 1024
#define DEP   4

typedef short bf16x8 __attribute__((ext_vector_type(8)));
typedef float f32x16 __attribute__((ext_vector_type(16)));

static __device__ __forceinline__ unsigned short f2bf(float f) {
  unsigned int u = __float_as_uint(f);
  u += 0x7FFFu + ((u >> 16) & 1u);   // RNE; inputs are normal randn, no NaN/Inf
  return (unsigned short)(u >> 16);
}

// global -> LDS direct copy, 16B/lane. LDS dest wave-uniform (HW adds lane*16).
static __device__ __forceinline__ void gld16(const void* g, void* l) {
  __builtin_amdgcn_global_load_lds(
      (const __attribute__((address_space(1))) unsigned int*)g,
      (__attribute__((address_space(3))) unsigned int*)(uintptr_t)l, 16, 0, 0);
}

// ---------------- kernel 1: table convert/swizzle + DIRECT-LINE encode ------
// blocks [0,64): build Tswz (R10 code, proven). blocks [64, 64+1024): encode
// 16 rows each via direct line reads: a subvec = exactly one aligned 64-B
// line and the tree's element indices are depth-fixed -> 16 independent
// scalar loads/thread (4 lines), no xs staging, no x barrier, 9 KiB LDS.
// (R14 lesson: this was bundled with a bad mfma change; testing it alone.)
__global__ __launch_bounds__(256) void prep_k(
    const float* __restrict__ x, const int* __restrict__ split_idxs,
    const float* __restrict__ split_vals, const float* __restrict__ Tg,
    unsigned char* __restrict__ codes, unsigned int* __restrict__ Tswz) {
  const int t = threadIdx.x;

  if (blockIdx.x < 64) {
    const int img = blockIdx.x;                   // = g8*8 + ch
    const int g = img >> 3, ch = img & 7;
    unsigned int* dst = Tswz + (size_t)img * 8192; // 8192 u32 = 32 KiB image
    const int colq = t & 31, kp = (t >> 5) & 7;
    #pragma unroll
    for (int cl = 0; cl < 8; ++cl) {
      const float* g0 = Tg + ((size_t)((ch * 8 + cl) * KCODE + 2 * kp)) * DOUTN
                        + g * 128 + colq * 4;
      float4 r0 = *(const float4*)g0;             // k=2kp   (coalesced)
      float4 r1 = *(const float4*)(g0 + DOUTN);   // k=2kp+1
      unsigned int pk[4] = {
        f2bf(r0.x) | ((unsigned int)f2bf(r1.x) << 16),
        f2bf(r0.y) | ((unsigned int)f2bf(r1.y) << 16),
        f2bf(r0.z) | ((unsigned int)f2bf(r1.z) << 16),
        f2bf(r0.w) | ((unsigned int)f2bf(r1.w) << 16)};
      unsigned key = (unsigned)(colq & 7) << 2;   // XOR on u32-idx bits[4:2]
      #pragma unroll
      for (int j = 0; j < 4; ++j)
        dst[cl * 1024 + ((((unsigned)(colq * 4 + j)) * 8 + (unsigned)kp) ^ key)]
            = pk[j];
    }
    return;
  }

  // ---- direct-line encode: 16 rows/block; thread = (c, 4 rows) ----
  __shared__ int   sidxT[DEP * CBN];               // [d][c]
  __shared__ float svalT[DEP * (KCODE / 2) * CBN]; // [d][e][c] (bank = c&31)
  if (t < DEP * CBN) {
    int d = t >> 6, c = t & 63;
    sidxT[t] = split_idxs[c * DEP + d];
  }
  #pragma unroll
  for (int i = 0; i < 8; ++i) {
    int idx = t + i * 256;
    int c = idx & 63, de = idx >> 6, d = de >> 3, e = de & 7;
    svalT[idx] = split_vals[(c * DEP + d) * (KCODE / 2) + e];
  }
  __syncthreads();

  const int c = t & 63, rg = t >> 6;               // 4 row-groups x 4 rows
  const size_t r0 = (size_t)(blockIdx.x - 64) * 16 + rg * 4;
  const float* xr = x + r0 * DOUTN + c * SUBV;
  const int si0 = sidxT[c],       si1 = sidxT[64 + c],
            si2 = sidxT[128 + c], si3 = sidxT[192 + c];
  float xv[4][4];
  #pragma unroll
  for (int i = 0; i < 4; ++i) {                    // 16 independent loads
    const float* xri = xr + (size_t)i * DOUTN;     // all 4 on ONE 64-B line
    xv[i][0] = xri[si0]; xv[i][1] = xri[si1];
    xv[i][2] = xri[si2]; xv[i][3] = xri[si3];
  }
  #pragma unroll
  for (int i = 0; i < 4; ++i) {
    int e = 0;
    #pragma unroll
    for (int d = 0; d < DEP; ++d) {
      float th = svalT[(d * 8 + e) * 64 + c];
      e = 2 * e + (xv[i][d] > th ? 1 : 0);
    }
    codes[(r0 + i) * CBN + c] = (unsigned char)e;
  }
}

// ---------------- kernel 2: one-hot MFMA gather-accumulate (R13 verbatim) ---
// grid (16 colgroups, 16 rowgroups) = 256 blocks = 1/CU; 1024 thr = 16 waves.
// One-shot gld16 stage, ONE barrier, free-run, wid-stagger, single epilogue.
// 64x64 wave (rt=2 x ct=2), u64-shift A-build, one-ahead prefetch of codes
// and B-frags, bias folded into acc init. Proven ~37 us.
__global__ __launch_bounds__(1024, 4) void maddness_mfma(
    const unsigned int* __restrict__ Tswz, const float* __restrict__ bias,
    const unsigned char* __restrict__ codes, float* __restrict__ out) {
  __shared__ __align__(16) unsigned int Tb[32768];   // 128 KiB: [ch8][cl8][512 u32]

  const int t = threadIdx.x;
  const int wid = t >> 6, lane = t & 63, lrow = lane & 31, h = lane >> 5;
  const int g16 = blockIdx.x, g8 = g16 >> 1, half = g16 & 1;
  const int n0 = blockIdx.y * 1024;
  const char* img = (const char*)Tswz + (size_t)g8 * 8 * 32768;

  // stage all 8 chunk half-images: 128 segs of 1024 B; wave stages 8 (R7 map)
  #pragma unroll
  for (int i = 0; i < 8; ++i) {
    int gs = wid * 8 + i;
    int ch = gs >> 4, s16 = gs & 15, cl = s16 >> 1, pc = s16 & 1;
    gld16(img + ch * 32768 + cl * 4096 + half * 2048 + pc * 1024 + lane * 16,
          (char*)Tb + gs * 1024);
  }

  // bias folded into acc init (col is lane-constant)
  const float bv0 = bias[g16 * 64 + lrow];
  const float bv1 = bias[g16 * 64 + 32 + lrow];
  f32x16 acc[2][2];
  #pragma unroll
  for (int rt = 0; rt < 2; ++rt)
    #pragma unroll
    for (int e = 0; e < 16; ++e) { acc[rt][0][e] = bv0; acc[rt][1][e] = bv1; }

  const unsigned char* crow0 = codes + (size_t)(n0 + wid * 64 + lrow) * CBN;
  const unsigned char* crow1 = crow0 + 32 * CBN;
  const unsigned h2 = 2u * (unsigned)h, h2p = h2 + 1u;
  const unsigned rb0 = ((unsigned)lrow * 16 + (unsigned)h * 8)
                     ^ ((((unsigned)lrow >> 2) & 7u) << 3);
  const unsigned cl32 = (unsigned)lrow + 32u;
  const unsigned rb1 = (cl32 * 16 + (unsigned)h * 8)
                     ^ (((cl32 >> 2) & 7u) << 3);

  __syncthreads();                                  // the ONLY barrier

  // software pipeline heads: codes for i=0, B-frags for (i=0, cl=0)
  const int ch0 = wid & 7;
  unsigned long long qA0 = *(const unsigned long long*)(crow0 + ch0 * 8);
  unsigned long long qA1 = *(const unsigned long long*)(crow1 + ch0 * 8);
  const unsigned short* tbc = (const unsigned short*)Tb + ch0 * 8192;
  bf16x8 bP0 = *(const bf16x8*)(tbc + rb0);
  bf16x8 bP1 = *(const bf16x8*)(tbc + rb1);

  #pragma unroll
  for (int i = 0; i < 8; ++i) {
    const int chn = (wid + i + 1) & 7;
    const unsigned short* tbn = (const unsigned short*)Tb + chn * 8192;
    const unsigned long long q0 = qA0, q1 = qA1;
    if (i < 7) {                                    // prefetch next codes
      qA0 = *(const unsigned long long*)(crow0 + chn * 8);
      qA1 = *(const unsigned long long*)(crow1 + chn * 8);
    }
    #pragma unroll
    for (int cl = 0; cl < 8; ++cl) {
      const bf16x8 b0 = bP0, b1 = bP1;
      if (!(i == 7 && cl == 7)) {                   // prefetch next B-frags
        const unsigned short* tnx = (cl == 7) ? tbn : (tbc + (cl + 1) * 1024);
        bP0 = *(const bf16x8*)(tnx + rb0);
        bP1 = *(const bf16x8*)(tnx + rb1);
      }
      #pragma unroll
      for (int rt = 0; rt < 2; ++rt) {
        const unsigned q32 =
            (unsigned)((rt ? q1 : q0) >> ((cl & 4) ? 32 : 0));
        const unsigned bpos = 8u * (unsigned)(cl & 3);
        const unsigned sh  = (q32 >> bpos) & 3u;        // c & 3
        const unsigned key = (q32 >> (bpos + 2)) & 3u;  // c >> 2
        const unsigned long long tt = 0x3F80ULL << (sh << 4);
        union { unsigned long long q[2]; bf16x8 v; } A;
        A.q[0] = (key == h2)  ? tt : 0ULL;
        A.q[1] = (key == h2p) ? tt : 0ULL;
        acc[rt][0] = __builtin_amdgcn_mfma_f32_32x32x16_bf16(A.v, b0, acc[rt][0], 0, 0, 0);
        acc[rt][1] = __builtin_amdgcn_mfma_f32_32x32x16_bf16(A.v, b1, acc[rt][1], 0, 0, 0);
      }
    }
    tbc = tbn;
  }

  // single epilogue (bias already in acc):
  // D layout col=lane&31, row=(reg&3)+8*(reg>>2)+4*(lane>>5)
  #pragma unroll
  for (int ct = 0; ct < 2; ++ct) {
    const int col = g16 * 64 + ct * 32 + lrow;
    #pragma unroll
    for (int rt = 0; rt < 2; ++rt)
      #pragma unroll
      for (int r = 0; r < 16; ++r) {
        int row = n0 + wid * 64 + rt * 32 + (r & 3) + 8 * (r >> 2) + 4 * h;
        out[(size_t)row * DOUTN + col] = acc[rt][ct][r];
      }
  }
}

extern "C" void kernel_launch(void* const* d_in, const int* in_sizes, int n_in,
                              void* d_out, int out_size, void* d_ws, size_t ws_size,
                              hipStream_t stream) {
  const float* x    = (const float*)d_in[0];
  const int*   sidx = (const int*)d_in[1];
  const float* sval = (const float*)d_in[2];
  const float* Tg   = (const float*)d_in[3];
  const float* bias = (const float*)d_in[4];
  float* out = (float*)d_out;
  unsigned char* codes = (unsigned char*)d_ws;                       // 1 MiB
  unsigned int*  Tswz  = (unsigned int*)((char*)d_ws + (1 << 20));   // 2 MiB

  prep_k<<<64 + NN / 16, 256, 0, stream>>>(x, sidx, sval, Tg, codes, Tswz);
  maddness_mfma<<<dim3(16, 16), 1024, 0, stream>>>(Tswz, bias, codes, out);
}